// Round 2
// baseline (349.163 us; speedup 1.0000x reference)
//
#include <hip/hip_runtime.h>
#include <float.h>

#define BATCH 4

// Pack dst points as (-2x, -2y, -2z, |q|^2) and initialize out to +FLT_MAX.
__global__ void chamfer_prep(const float* __restrict__ xyz1,
                             const float* __restrict__ xyz2,
                             float4* __restrict__ pk1,
                             float4* __restrict__ pk2,
                             float* __restrict__ out,
                             int n1, int n2, int out_n) {
    int i = blockIdx.x * blockDim.x + threadIdx.x;
    if (i < n1) {
        float x = xyz1[3 * (size_t)i], y = xyz1[3 * (size_t)i + 1], z = xyz1[3 * (size_t)i + 2];
        pk1[i] = make_float4(-2.f * x, -2.f * y, -2.f * z, fmaf(x, x, fmaf(y, y, z * z)));
    }
    if (i < n2) {
        float x = xyz2[3 * (size_t)i], y = xyz2[3 * (size_t)i + 1], z = xyz2[3 * (size_t)i + 2];
        pk2[i] = make_float4(-2.f * x, -2.f * y, -2.f * z, fmaf(x, x, fmaf(y, y, z * z)));
    }
    if (i < out_n) out[i] = FLT_MAX;
}

// One thread per src point; scans CHUNK packed dst points. dst address is
// wave-uniform (depends only on block/loop counter) -> compiler emits scalar
// s_load into SGPRs: 0 memory ops on the vector pipes. 5 VALU/point:
//   dot = q2x*px; fma(q2y,py); fma(q2z,pz); e = dot + qsq; min
// min_j(|p-q|^2) = psq + min_j(qsq - 2 p.q), psq added once at the end.
template<int TPB, int CHUNK>
__global__ __launch_bounds__(TPB) void chamfer_min_packed(
        const float* __restrict__ src,    // (B, Nsrc, 3) raw
        const float4* __restrict__ dstp,  // (B, Mdst) packed
        float* __restrict__ out,          // (B, Nsrc)
        int Nsrc, int Mdst) {
    const int b  = blockIdx.x;
    const int i  = blockIdx.y * TPB + threadIdx.x;
    const int j0 = blockIdx.z * CHUNK;

    const float* p = src + ((size_t)b * Nsrc + i) * 3;
    const float px = p[0], py = p[1], pz = p[2];
    const float psq = fmaf(px, px, fmaf(py, py, pz * pz));

    const float4* q = dstp + (size_t)b * Mdst + j0;

    float m = FLT_MAX;
    #pragma unroll 8
    for (int j = 0; j < CHUNK; ++j) {
        const float4 qq = q[j];
        float dot = qq.x * px;
        dot = fmaf(qq.y, py, dot);
        dot = fmaf(qq.z, pz, dot);
        const float e = dot + qq.w;
        m = fminf(m, e);
    }

    // True squared distance is >= 0; clamp rounding negatives so the
    // int-punned atomicMin ordering stays monotonic.
    const float d = fmaxf(psq + m, 0.0f);
    atomicMin((int*)&out[(size_t)b * Nsrc + i], __float_as_int(d));
}

// ---- Fallback path (only if d_ws is too small to hold packed arrays) ----
__global__ void chamfer_init_out(float* __restrict__ out, int n) {
    int i = blockIdx.x * blockDim.x + threadIdx.x;
    if (i < n) out[i] = FLT_MAX;
}

template<int TPB, int CHUNK>
__global__ __launch_bounds__(TPB) void chamfer_min_lds(
        const float* __restrict__ src, const float* __restrict__ dst,
        float* __restrict__ out, int N, int M) {
    __shared__ float s[CHUNK * 3];
    const int b  = blockIdx.x;
    const int i  = blockIdx.y * TPB + threadIdx.x;
    const int j0 = blockIdx.z * CHUNK;
    const float* p = src + ((size_t)b * N + i) * 3;
    const float px = p[0], py = p[1], pz = p[2];
    const float* dchunk = dst + ((size_t)b * M + j0) * 3;
    constexpr int NVEC = CHUNK * 3 / 4;
    for (int t = threadIdx.x; t < NVEC; t += TPB)
        ((float4*)s)[t] = ((const float4*)dchunk)[t];
    __syncthreads();
    float best = FLT_MAX;
    #pragma unroll 8
    for (int j = 0; j < CHUNK; ++j) {
        const float dx = px - s[3 * j + 0];
        const float dy = py - s[3 * j + 1];
        const float dz = pz - s[3 * j + 2];
        float d = dx * dx;
        d = fmaf(dy, dy, d);
        d = fmaf(dz, dz, d);
        best = fminf(best, d);
    }
    atomicMin((int*)&out[(size_t)b * N + i], __float_as_int(best));
}

extern "C" void kernel_launch(void* const* d_in, const int* in_sizes, int n_in,
                              void* d_out, int out_size, void* d_ws, size_t ws_size,
                              hipStream_t stream) {
    const float* xyz1 = (const float*)d_in[0];
    const float* xyz2 = (const float*)d_in[1];
    float* out = (float*)d_out;

    const int N = in_sizes[0] / (BATCH * 3);  // 8192
    const int M = in_sizes[1] / (BATCH * 3);  // 8192
    const int n1 = BATCH * N, n2 = BATCH * M;

    constexpr int TPB = 256;
    constexpr int CHUNK = 512;  // Z = 8192/512 = 16 -> 2048 blocks/launch

    const size_t need = ((size_t)n1 + (size_t)n2) * sizeof(float4);
    if (ws_size >= need) {
        float4* pk1 = (float4*)d_ws;
        float4* pk2 = pk1 + n1;
        int prep_n = out_size > n1 ? out_size : n1;
        if (n2 > prep_n) prep_n = n2;
        chamfer_prep<<<(prep_n + TPB - 1) / TPB, TPB, 0, stream>>>(
            xyz1, xyz2, pk1, pk2, out, n1, n2, out_size);

        dim3 g1(BATCH, N / TPB, M / CHUNK);
        chamfer_min_packed<TPB, CHUNK><<<g1, TPB, 0, stream>>>(xyz1, pk2, out, N, M);
        dim3 g2(BATCH, M / TPB, N / CHUNK);
        chamfer_min_packed<TPB, CHUNK><<<g2, TPB, 0, stream>>>(xyz2, pk1, out + n1, M, N);
    } else {
        // Fallback: proven round-1 LDS path.
        constexpr int LCHUNK = 1024;
        chamfer_init_out<<<(out_size + TPB - 1) / TPB, TPB, 0, stream>>>(out, out_size);
        dim3 g1(BATCH, N / TPB, M / LCHUNK);
        chamfer_min_lds<TPB, LCHUNK><<<g1, TPB, 0, stream>>>(xyz1, xyz2, out, N, M);
        dim3 g2(BATCH, M / TPB, N / LCHUNK);
        chamfer_min_lds<TPB, LCHUNK><<<g2, TPB, 0, stream>>>(xyz2, xyz1, out + n1, M, N);
    }
}

// Round 3
// 50.331 us; speedup vs baseline: 6.9373x; 6.9373x over previous
//
#include <hip/hip_runtime.h>
#include <float.h>

#define BATCH 4

// Pack points as (-2x, -2y, -2z, |q|^2) for both sets; init out to +FLT_MAX.
__global__ void chamfer_prep(const float* __restrict__ xyz1,
                             const float* __restrict__ xyz2,
                             float4* __restrict__ pk1,
                             float4* __restrict__ pk2,
                             float* __restrict__ out,
                             int n1, int n2, int out_n) {
    int i = blockIdx.x * blockDim.x + threadIdx.x;
    if (i < n1) {
        float x = xyz1[3 * (size_t)i], y = xyz1[3 * (size_t)i + 1], z = xyz1[3 * (size_t)i + 2];
        pk1[i] = make_float4(-2.f * x, -2.f * y, -2.f * z, fmaf(x, x, fmaf(y, y, z * z)));
    }
    if (i < n2) {
        float x = xyz2[3 * (size_t)i], y = xyz2[3 * (size_t)i + 1], z = xyz2[3 * (size_t)i + 2];
        pk2[i] = make_float4(-2.f * x, -2.f * y, -2.f * z, fmaf(x, x, fmaf(y, y, z * z)));
    }
    if (i < out_n) out[i] = FLT_MAX;
}

// Fused both-direction kernel. Each block: one (dir, batch, src-tile, dst-chunk).
// Stage CHUNK packed dst points in LDS; each thread holds P src points in
// registers; inner loop = 1 broadcast ds_read_b128 + P*(3 fma + 1 min).
// min_j |p-q|^2 = psq + min_j( qsq - 2 p.q ); psq applied once in epilogue.
template<int TPB, int CHUNK, int P>
__global__ __launch_bounds__(TPB) void chamfer_fused(
        const float* __restrict__ xyz1,   // (B, N, 3) raw
        const float* __restrict__ xyz2,   // (B, M, 3) raw
        const float4* __restrict__ pk1,   // (B, N) packed
        const float4* __restrict__ pk2,   // (B, M) packed
        float* __restrict__ out,          // (B*N) ++ (B*M)
        int N, int M, int blocks_dir0) {
    __shared__ float4 s[CHUNK];

    int bid = blockIdx.x;
    const int dir = (bid >= blocks_dir0) ? 1 : 0;
    if (dir) bid -= blocks_dir0;

    const int Nsrc = dir ? M : N;
    const int Mdst = dir ? N : M;
    const float* src        = dir ? xyz2 : xyz1;
    const float4* dstp      = dir ? pk1  : pk2;
    float* outd             = dir ? (out + (size_t)BATCH * N) : out;

    const int YT = Nsrc / (TPB * P);   // src tiles
    const int Z  = Mdst / CHUNK;       // dst chunks
    const int b  = bid / (YT * Z);
    const int r  = bid % (YT * Z);
    const int yt = r / Z;
    const int z  = r % Z;

    // Stage the dst chunk (CHUNK * 16B) into LDS.
    const float4* dchunk = dstp + (size_t)b * Mdst + (size_t)z * CHUNK;
    #pragma unroll
    for (int t = threadIdx.x; t < CHUNK; t += TPB)
        s[t] = dchunk[t];

    // Load P src points into registers while the staging completes.
    const int i0 = yt * (TPB * P) + threadIdx.x;
    float px[P], py[P], pz[P], psq[P], m[P];
    #pragma unroll
    for (int k = 0; k < P; ++k) {
        const int i = i0 + k * TPB;
        const float* p = src + ((size_t)b * Nsrc + i) * 3;
        px[k] = p[0]; py[k] = p[1]; pz[k] = p[2];
        psq[k] = fmaf(px[k], px[k], fmaf(py[k], py[k], pz[k] * pz[k]));
        m[k] = FLT_MAX;
    }
    __syncthreads();

    #pragma unroll 4
    for (int j = 0; j < CHUNK; ++j) {
        const float4 qq = s[j];   // broadcast, conflict-free
        #pragma unroll
        for (int k = 0; k < P; ++k) {
            const float e = fmaf(qq.x, px[k],
                             fmaf(qq.y, py[k],
                              fmaf(qq.z, pz[k], qq.w)));
            m[k] = fminf(m[k], e);
        }
    }

    #pragma unroll
    for (int k = 0; k < P; ++k) {
        const int i = i0 + k * TPB;
        const float d = fmaxf(psq[k] + m[k], 0.0f);  // >=0 keeps int-min ordering
        atomicMin((int*)&outd[(size_t)b * Nsrc + i], __float_as_int(d));
    }
}

// ---- Fallback path (ws too small): proven round-1 LDS kernel ----
__global__ void chamfer_init_out(float* __restrict__ out, int n) {
    int i = blockIdx.x * blockDim.x + threadIdx.x;
    if (i < n) out[i] = FLT_MAX;
}

template<int TPB, int CHUNK>
__global__ __launch_bounds__(TPB) void chamfer_min_lds(
        const float* __restrict__ src, const float* __restrict__ dst,
        float* __restrict__ out, int N, int M) {
    __shared__ float s[CHUNK * 3];
    const int b  = blockIdx.x;
    const int i  = blockIdx.y * TPB + threadIdx.x;
    const int j0 = blockIdx.z * CHUNK;
    const float* p = src + ((size_t)b * N + i) * 3;
    const float px = p[0], py = p[1], pz = p[2];
    const float* dchunk = dst + ((size_t)b * M + j0) * 3;
    constexpr int NVEC = CHUNK * 3 / 4;
    for (int t = threadIdx.x; t < NVEC; t += TPB)
        ((float4*)s)[t] = ((const float4*)dchunk)[t];
    __syncthreads();
    float best = FLT_MAX;
    #pragma unroll 8
    for (int j = 0; j < CHUNK; ++j) {
        const float dx = px - s[3 * j + 0];
        const float dy = py - s[3 * j + 1];
        const float dz = pz - s[3 * j + 2];
        float d = dx * dx;
        d = fmaf(dy, dy, d);
        d = fmaf(dz, dz, d);
        best = fminf(best, d);
    }
    atomicMin((int*)&out[(size_t)b * N + i], __float_as_int(best));
}

extern "C" void kernel_launch(void* const* d_in, const int* in_sizes, int n_in,
                              void* d_out, int out_size, void* d_ws, size_t ws_size,
                              hipStream_t stream) {
    const float* xyz1 = (const float*)d_in[0];
    const float* xyz2 = (const float*)d_in[1];
    float* out = (float*)d_out;

    const int N = in_sizes[0] / (BATCH * 3);  // 8192
    const int M = in_sizes[1] / (BATCH * 3);  // 8192
    const int n1 = BATCH * N, n2 = BATCH * M;

    constexpr int TPB = 256;
    constexpr int CHUNK = 512;   // 8 KiB LDS
    constexpr int P = 4;

    const size_t need = ((size_t)n1 + (size_t)n2) * sizeof(float4);
    const bool divisible = (N % (TPB * P) == 0) && (M % (TPB * P) == 0) &&
                           (N % CHUNK == 0) && (M % CHUNK == 0);

    if (ws_size >= need && divisible) {
        float4* pk1 = (float4*)d_ws;
        float4* pk2 = pk1 + n1;
        int prep_n = out_size > n1 ? out_size : n1;
        if (n2 > prep_n) prep_n = n2;
        chamfer_prep<<<(prep_n + TPB - 1) / TPB, TPB, 0, stream>>>(
            xyz1, xyz2, pk1, pk2, out, n1, n2, out_size);

        const int blocks_dir0 = BATCH * (N / (TPB * P)) * (M / CHUNK);
        const int blocks_dir1 = BATCH * (M / (TPB * P)) * (N / CHUNK);
        chamfer_fused<TPB, CHUNK, P><<<blocks_dir0 + blocks_dir1, TPB, 0, stream>>>(
            xyz1, xyz2, pk1, pk2, out, N, M, blocks_dir0);
    } else {
        constexpr int LCHUNK = 1024;
        chamfer_init_out<<<(out_size + TPB - 1) / TPB, TPB, 0, stream>>>(out, out_size);
        dim3 g1(BATCH, N / TPB, M / LCHUNK);
        chamfer_min_lds<TPB, LCHUNK><<<g1, TPB, 0, stream>>>(xyz1, xyz2, out, N, M);
        dim3 g2(BATCH, M / TPB, N / LCHUNK);
        chamfer_min_lds<TPB, LCHUNK><<<g2, TPB, 0, stream>>>(xyz2, xyz1, out + n1, M, N);
    }
}

// Round 4
// 49.343 us; speedup vs baseline: 7.0762x; 1.0200x over previous
//
#include <hip/hip_runtime.h>
#include <float.h>

#define BATCH 4

typedef float f32x2 __attribute__((ext_vector_type(2)));

// Pack points as (-2x, -2y, -2z, |q|^2) for both sets; init out to +FLT_MAX.
__global__ void chamfer_prep(const float* __restrict__ xyz1,
                             const float* __restrict__ xyz2,
                             float4* __restrict__ pk1,
                             float4* __restrict__ pk2,
                             float* __restrict__ out,
                             int n1, int n2, int out_n) {
    int i = blockIdx.x * blockDim.x + threadIdx.x;
    if (i < n1) {
        float x = xyz1[3 * (size_t)i], y = xyz1[3 * (size_t)i + 1], z = xyz1[3 * (size_t)i + 2];
        pk1[i] = make_float4(-2.f * x, -2.f * y, -2.f * z, fmaf(x, x, fmaf(y, y, z * z)));
    }
    if (i < n2) {
        float x = xyz2[3 * (size_t)i], y = xyz2[3 * (size_t)i + 1], z = xyz2[3 * (size_t)i + 2];
        pk2[i] = make_float4(-2.f * x, -2.f * y, -2.f * z, fmaf(x, x, fmaf(y, y, z * z)));
    }
    if (i < out_n) out[i] = FLT_MAX;
}

// Fused both-direction kernel, packed-fp32 inner loop.
// LDS chunk is transposed into dst-point PAIRS:
//   s[2t]   = (x0, x1, y0, y1)
//   s[2t+1] = (z0, z1, w0, w1)
// Per pair of dst points and per src point:
//   e01 = pk_fma(x01, px, pk_fma(y01, py, pk_fma(z01, pz, w01)))
//   m   = min3(m, e0, e1)
// min_j |p-q|^2 = psq + min_j( qsq - 2 p.q ); psq applied in epilogue.
template<int TPB, int CHUNK, int P>
__global__ __launch_bounds__(TPB) void chamfer_fused(
        const float* __restrict__ xyz1,   // (B, N, 3) raw
        const float* __restrict__ xyz2,   // (B, M, 3) raw
        const float4* __restrict__ pk1,   // (B, N) packed
        const float4* __restrict__ pk2,   // (B, M) packed
        float* __restrict__ out,          // (B*N) ++ (B*M)
        int N, int M, int blocks_dir0) {
    __shared__ float4 s[CHUNK];

    int bid = blockIdx.x;
    const int dir = (bid >= blocks_dir0) ? 1 : 0;
    if (dir) bid -= blocks_dir0;

    const int Nsrc = dir ? M : N;
    const int Mdst = dir ? N : M;
    const float* src   = dir ? xyz2 : xyz1;
    const float4* dstp = dir ? pk1  : pk2;
    float* outd        = dir ? (out + (size_t)BATCH * N) : out;

    const int YT = Nsrc / (TPB * P);   // src tiles
    const int Z  = Mdst / CHUNK;       // dst chunks
    const int b  = bid / (YT * Z);
    const int r  = bid % (YT * Z);
    const int yt = r / Z;
    const int z  = r % Z;

    // Stage + transpose the dst chunk into pair-packed layout.
    const float4* dchunk = dstp + (size_t)b * Mdst + (size_t)z * CHUNK;
    for (int t = threadIdx.x; t < CHUNK / 2; t += TPB) {
        const float4 q0 = dchunk[2 * t];
        const float4 q1 = dchunk[2 * t + 1];
        s[2 * t]     = make_float4(q0.x, q1.x, q0.y, q1.y);
        s[2 * t + 1] = make_float4(q0.z, q1.z, q0.w, q1.w);
    }

    // P src points per thread, components duplicated for packed math.
    const int i0 = yt * (TPB * P) + threadIdx.x;
    f32x2 px[P], py[P], pz[P];
    float psq[P], m[P];
    #pragma unroll
    for (int k = 0; k < P; ++k) {
        const int i = i0 + k * TPB;
        const float* p = src + ((size_t)b * Nsrc + i) * 3;
        const float x = p[0], y = p[1], zc = p[2];
        px[k] = (f32x2){x, x};
        py[k] = (f32x2){y, y};
        pz[k] = (f32x2){zc, zc};
        psq[k] = fmaf(x, x, fmaf(y, y, zc * zc));
        m[k] = FLT_MAX;
    }
    __syncthreads();

    #pragma unroll 4
    for (int jj = 0; jj < CHUNK / 2; ++jj) {
        const float4 A = s[2 * jj];       // (x0,x1,y0,y1) broadcast
        const float4 B = s[2 * jj + 1];   // (z0,z1,w0,w1) broadcast
        const f32x2 xq = (f32x2){A.x, A.y};
        const f32x2 yq = (f32x2){A.z, A.w};
        const f32x2 zq = (f32x2){B.x, B.y};
        const f32x2 wq = (f32x2){B.z, B.w};
        #pragma unroll
        for (int k = 0; k < P; ++k) {
            const f32x2 e = __builtin_elementwise_fma(xq, px[k],
                             __builtin_elementwise_fma(yq, py[k],
                              __builtin_elementwise_fma(zq, pz[k], wq)));
            m[k] = fminf(fminf(m[k], e.x), e.y);   // -> v_min3_f32
        }
    }

    #pragma unroll
    for (int k = 0; k < P; ++k) {
        const int i = i0 + k * TPB;
        const float d = fmaxf(psq[k] + m[k], 0.0f);  // >=0 keeps int-min ordering
        atomicMin((int*)&outd[(size_t)b * Nsrc + i], __float_as_int(d));
    }
}

// ---- Fallback path (ws too small / odd sizes): proven round-1 LDS kernel ----
__global__ void chamfer_init_out(float* __restrict__ out, int n) {
    int i = blockIdx.x * blockDim.x + threadIdx.x;
    if (i < n) out[i] = FLT_MAX;
}

template<int TPB, int CHUNK>
__global__ __launch_bounds__(TPB) void chamfer_min_lds(
        const float* __restrict__ src, const float* __restrict__ dst,
        float* __restrict__ out, int N, int M) {
    __shared__ float s[CHUNK * 3];
    const int b  = blockIdx.x;
    const int i  = blockIdx.y * TPB + threadIdx.x;
    const int j0 = blockIdx.z * CHUNK;
    const float* p = src + ((size_t)b * N + i) * 3;
    const float px = p[0], py = p[1], pz = p[2];
    const float* dchunk = dst + ((size_t)b * M + j0) * 3;
    constexpr int NVEC = CHUNK * 3 / 4;
    for (int t = threadIdx.x; t < NVEC; t += TPB)
        ((float4*)s)[t] = ((const float4*)dchunk)[t];
    __syncthreads();
    float best = FLT_MAX;
    #pragma unroll 8
    for (int j = 0; j < CHUNK; ++j) {
        const float dx = px - s[3 * j + 0];
        const float dy = py - s[3 * j + 1];
        const float dz = pz - s[3 * j + 2];
        float d = dx * dx;
        d = fmaf(dy, dy, d);
        d = fmaf(dz, dz, d);
        best = fminf(best, d);
    }
    atomicMin((int*)&out[(size_t)b * N + i], __float_as_int(best));
}

extern "C" void kernel_launch(void* const* d_in, const int* in_sizes, int n_in,
                              void* d_out, int out_size, void* d_ws, size_t ws_size,
                              hipStream_t stream) {
    const float* xyz1 = (const float*)d_in[0];
    const float* xyz2 = (const float*)d_in[1];
    float* out = (float*)d_out;

    const int N = in_sizes[0] / (BATCH * 3);  // 8192
    const int M = in_sizes[1] / (BATCH * 3);  // 8192
    const int n1 = BATCH * N, n2 = BATCH * M;

    constexpr int TPB = 256;
    constexpr int CHUNK = 256;   // 4 KiB LDS, Z=32 -> 1024 blocks total
    constexpr int P = 8;

    const size_t need = ((size_t)n1 + (size_t)n2) * sizeof(float4);
    const bool divisible = (N % (TPB * P) == 0) && (M % (TPB * P) == 0) &&
                           (N % CHUNK == 0) && (M % CHUNK == 0);

    if (ws_size >= need && divisible) {
        float4* pk1 = (float4*)d_ws;
        float4* pk2 = pk1 + n1;
        int prep_n = out_size > n1 ? out_size : n1;
        if (n2 > prep_n) prep_n = n2;
        chamfer_prep<<<(prep_n + TPB - 1) / TPB, TPB, 0, stream>>>(
            xyz1, xyz2, pk1, pk2, out, n1, n2, out_size);

        const int blocks_dir0 = BATCH * (N / (TPB * P)) * (M / CHUNK);
        const int blocks_dir1 = BATCH * (M / (TPB * P)) * (N / CHUNK);
        chamfer_fused<TPB, CHUNK, P><<<blocks_dir0 + blocks_dir1, TPB, 0, stream>>>(
            xyz1, xyz2, pk1, pk2, out, N, M, blocks_dir0);
    } else {
        constexpr int LCHUNK = 1024;
        chamfer_init_out<<<(out_size + TPB - 1) / TPB, TPB, 0, stream>>>(out, out_size);
        dim3 g1(BATCH, N / TPB, M / LCHUNK);
        chamfer_min_lds<TPB, LCHUNK><<<g1, TPB, 0, stream>>>(xyz1, xyz2, out, N, M);
        dim3 g2(BATCH, M / TPB, N / LCHUNK);
        chamfer_min_lds<TPB, LCHUNK><<<g2, TPB, 0, stream>>>(xyz2, xyz1, out + n1, M, N);
    }
}